// Round 1
// baseline (467.396 us; speedup 1.0000x reference)
//
#include <hip/hip_runtime.h>
#include <math.h>

#define NC 10      // classes
#define NP 5       // proxies per class
#define NCP 50     // NC*NP
#define ND 256     // feature dim
#define FTEMP 0.05f
#define FEPS  0.05f

// ---------------- workspace layout ----------------
// [0,400)        double acc[50]     sinkhorn column accumulators
// [400,640)      double abl[30]     A[10], B[10], L[10]
// [640,680)      int    counts[10]
// [680,880)      float  v[50]
// [1024, +4n)    float  u[n]
// [align512]     float  dis5[5n]

__global__ __launch_bounds__(64) void init_ws(double* __restrict__ acc,
                                              double* __restrict__ abl,
                                              int* __restrict__ counts,
                                              float* __restrict__ v) {
    int i = threadIdx.x;
    if (i < NCP) { acc[i] = 0.0; v[i] = 1.0f; }
    if (i < 3 * NC) abl[i] = 0.0;
    if (i < NC) counts[i] = 0;
}

// One wave per row: coalesced float4 load of the 256-float row, dot with the
// 5 proxies of the row's class (staged in LDS), butterfly-reduce 6 scalars.
__global__ __launch_bounds__(256) void pass_a(const float* __restrict__ feat,
                                              const float* __restrict__ proxy,
                                              const int* __restrict__ tgt,
                                              float* __restrict__ dis5,
                                              int* __restrict__ counts, int n) {
    __shared__ float4 sp[NCP * 64];   // 51200 B: all 50 proxies
    __shared__ int scnt[NC];
    for (int i = threadIdx.x; i < NCP * 64; i += blockDim.x)
        sp[i] = reinterpret_cast<const float4*>(proxy)[i];
    if (threadIdx.x < NC) scnt[threadIdx.x] = 0;
    __syncthreads();

    const int lane = threadIdx.x & 63;
    const int wid  = (blockIdx.x * blockDim.x + threadIdx.x) >> 6;
    const int nw   = (gridDim.x * blockDim.x) >> 6;

    for (int r = wid; r < n; r += nw) {
        const int t = tgt[r];
        float4 x = reinterpret_cast<const float4*>(feat)[(size_t)r * 64 + lane];
        const float4* pp = &sp[t * (NP * 64) + lane];
        float n2 = x.x * x.x + x.y * x.y + x.z * x.z + x.w * x.w;
        float4 p0 = pp[0], p1 = pp[64], p2 = pp[128], p3 = pp[192], p4 = pp[256];
        float d0 = x.x * p0.x + x.y * p0.y + x.z * p0.z + x.w * p0.w;
        float d1 = x.x * p1.x + x.y * p1.y + x.z * p1.z + x.w * p1.w;
        float d2 = x.x * p2.x + x.y * p2.y + x.z * p2.z + x.w * p2.w;
        float d3 = x.x * p3.x + x.y * p3.y + x.z * p3.z + x.w * p3.w;
        float d4 = x.x * p4.x + x.y * p4.y + x.z * p4.z + x.w * p4.w;
#pragma unroll
        for (int off = 32; off >= 1; off >>= 1) {
            n2 += __shfl_xor(n2, off);
            d0 += __shfl_xor(d0, off);
            d1 += __shfl_xor(d1, off);
            d2 += __shfl_xor(d2, off);
            d3 += __shfl_xor(d3, off);
            d4 += __shfl_xor(d4, off);
        }
        const float inv = 1.0f / fmaxf(sqrtf(n2), 1e-12f);
        if (lane < NP) {
            float dj = (lane == 0) ? d0 : (lane == 1) ? d1 : (lane == 2) ? d2
                     : (lane == 3) ? d3 : d4;
            dj = fminf(fmaxf(dj * inv, -10.0f), 10.0f);
            dis5[(size_t)r * NP + lane] = dj;
        }
        if (lane == 0) atomicAdd(&scnt[t], 1);
    }
    __syncthreads();
    if (threadIdx.x < NC) atomicAdd(&counts[threadIdx.x], scnt[threadIdx.x]);
}

// One sinkhorn iteration: u_i = 1/clip(dis_i . v[t_i]); acc[t][j] += dis_ij*u_i
__global__ __launch_bounds__(256) void sk_accum(const float* __restrict__ dis5,
                                                const int* __restrict__ tgt,
                                                const float* __restrict__ v,
                                                float* __restrict__ u,
                                                double* __restrict__ acc, int n) {
    __shared__ float sv[NCP];
    __shared__ double sacc[NCP];
    if (threadIdx.x < NCP) { sv[threadIdx.x] = v[threadIdx.x]; sacc[threadIdx.x] = 0.0; }
    __syncthreads();
    const int stride = gridDim.x * blockDim.x;
    for (int r = blockIdx.x * blockDim.x + threadIdx.x; r < n; r += stride) {
        const int t = tgt[r];
        const float* dr = &dis5[(size_t)r * NP];
        float d0 = dr[0], d1 = dr[1], d2 = dr[2], d3 = dr[3], d4 = dr[4];
        const float* vt = &sv[t * NP];
        float den = d0 * vt[0] + d1 * vt[1] + d2 * vt[2] + d3 * vt[3] + d4 * vt[4];
        float uu = 1.0f / fmaxf(den, 1e-10f);
        u[r] = uu;
        double* at = &sacc[t * NP];
        atomicAdd(&at[0], (double)(d0 * uu));
        atomicAdd(&at[1], (double)(d1 * uu));
        atomicAdd(&at[2], (double)(d2 * uu));
        atomicAdd(&at[3], (double)(d3 * uu));
        atomicAdd(&at[4], (double)(d4 * uu));
    }
    __syncthreads();
    if (threadIdx.x < NCP) atomicAdd(&acc[threadIdx.x], sacc[threadIdx.x]);
}

__global__ __launch_bounds__(64) void sk_finalize(double* __restrict__ acc,
                                                  float* __restrict__ v) {
    int i = threadIdx.x;
    if (i < NCP) {
        float s = (float)acc[i];
        v[i] = 1.0f / fmaxf(s, 1e-10f);
        acc[i] = 0.0;
    }
}

// Per-class A = sum Q*logits, B = sum Q, L = sum lse2
__global__ __launch_bounds__(256) void pass_c(const float* __restrict__ dis5,
                                              const int* __restrict__ tgt,
                                              const float* __restrict__ u,
                                              const float* __restrict__ v,
                                              double* __restrict__ abl, int n) {
    __shared__ float sv[NCP];
    __shared__ double sA[NC], sB[NC], sL[NC];
    if (threadIdx.x < NCP) sv[threadIdx.x] = v[threadIdx.x];
    if (threadIdx.x < NC) { sA[threadIdx.x] = 0.0; sB[threadIdx.x] = 0.0; sL[threadIdx.x] = 0.0; }
    __syncthreads();
    const int stride = gridDim.x * blockDim.x;
    for (int r = blockIdx.x * blockDim.x + threadIdx.x; r < n; r += stride) {
        const int t = tgt[r];
        const float* dr = &dis5[(size_t)r * NP];
        float d[NP];
#pragma unroll
        for (int j = 0; j < NP; ++j) d[j] = dr[j];
        // logits = log_softmax(d/TEMP)
        float a[NP], mx = -1e30f;
#pragma unroll
        for (int j = 0; j < NP; ++j) { a[j] = d[j] * (1.0f / FTEMP); mx = fmaxf(mx, a[j]); }
        float s = 0.0f;
#pragma unroll
        for (int j = 0; j < NP; ++j) s += expf(a[j] - mx);
        float lse = mx + logf(s);
        float lg[NP];
#pragma unroll
        for (int j = 0; j < NP; ++j) lg[j] = a[j] - lse;
        // lse2 = logsumexp(logits)  (== ~0 numerically, compute anyway)
        float mx2 = -1e30f;
#pragma unroll
        for (int j = 0; j < NP; ++j) mx2 = fmaxf(mx2, lg[j]);
        float s2 = 0.0f;
#pragma unroll
        for (int j = 0; j < NP; ++j) s2 += expf(lg[j] - mx2);
        float lse2 = mx2 + logf(s2);

        const float uu = u[r];
        const float* vt = &sv[t * NP];
        float rowA = 0.0f, rowB = 0.0f;
#pragma unroll
        for (int j = 0; j < NP; ++j) {
            float q = uu * expf(d[j] * (1.0f / FEPS)) * vt[j];
            rowB += q;
            rowA += q * lg[j];
        }
        atomicAdd(&sA[t], (double)rowA);
        atomicAdd(&sB[t], (double)rowB);
        atomicAdd(&sL[t], (double)lse2);
    }
    __syncthreads();
    if (threadIdx.x < NC) {
        atomicAdd(&abl[threadIdx.x], sA[threadIdx.x]);
        atomicAdd(&abl[NC + threadIdx.x], sB[threadIdx.x]);
        atomicAdd(&abl[2 * NC + threadIdx.x], sL[threadIdx.x]);
    }
}

// Single block: proxy Gram + pcon + mle -> scalar
__global__ __launch_bounds__(256) void finalize(const float* __restrict__ proxy,
                                                const double* __restrict__ abl,
                                                const int* __restrict__ counts,
                                                float* __restrict__ out) {
    __shared__ float G[NCP][NCP];
    for (int e = threadIdx.x; e < NCP * NCP; e += blockDim.x) {
        int i = e / NCP, j = e % NCP;
        float s = 0.0f;
        for (int k = 0; k < ND; ++k) s += proxy[i * ND + k] * proxy[j * ND + k];
        G[i][j] = s;
    }
    __syncthreads();

    double local = 0.0;
    // 100 (c,co) pairs x 5 rows
    for (int task = threadIdx.x; task < NC * NC * NP; task += blockDim.x) {
        int r = task % NP;
        int pi = task / NP;
        int co = pi % NC, c = pi / NC;
        float m[NP], mx = -1e30f;
#pragma unroll
        for (int j = 0; j < NP; ++j) {
            float g = G[c * NP + r][co * NP + j] * (1.0f / FTEMP);
            g = fminf(fmaxf(g, -10.0f), 10.0f);
            m[j] = g;
            mx = fmaxf(mx, g);
        }
        float s = 0.0f;
#pragma unroll
        for (int j = 0; j < NP; ++j) s += expf(m[j] - mx);
        float lse = mx + logf(s);
        // li[j] = m[j]-lse ; lse2 = logsumexp(li)
        float mx2 = -1e30f;
#pragma unroll
        for (int j = 0; j < NP; ++j) mx2 = fmaxf(mx2, m[j] - lse);
        float s2 = 0.0f;
#pragma unroll
        for (int j = 0; j < NP; ++j) s2 += expf(m[j] - lse - mx2);
        float lse2 = mx2 + logf(s2);

        if (co == c) {
            float lirr = m[r] - lse;
            local += -(double)(lirr - lse2) * (1.0 / NP);
        } else {
            local += (double)lse2 * (1.0 / NP);
        }
    }
    __shared__ double red[256];
    red[threadIdx.x] = local;
    __syncthreads();
    for (int off = 128; off >= 1; off >>= 1) {
        if (threadIdx.x < off) red[threadIdx.x] += red[threadIdx.x + off];
        __syncthreads();
    }
    if (threadIdx.x == 0) {
        double pcon = red[0];
        double mle = 0.0;
        for (int c = 0; c < NC; ++c) {
            int cnt = counts[c];
            if (cnt > 0) {
                double A = abl[c], B = abl[NC + c], L = abl[2 * NC + c];
                mle += -(A / B - L) / (double)cnt;
            }
        }
        out[0] = (float)((mle + pcon) / NC);
    }
}

extern "C" void kernel_launch(void* const* d_in, const int* in_sizes, int n_in,
                              void* d_out, int out_size, void* d_ws, size_t ws_size,
                              hipStream_t stream) {
    const float* feat  = (const float*)d_in[0];
    const float* proxy = (const float*)d_in[1];
    const int*   tgt   = (const int*)d_in[2];
    const int n = in_sizes[0] / ND;

    char* ws = (char*)d_ws;
    double* acc    = (double*)ws;                 // 50
    double* abl    = (double*)(ws + 400);         // 30
    int*    counts = (int*)(ws + 640);            // 10
    float*  v      = (float*)(ws + 680);          // 50
    float*  u      = (float*)(ws + 1024);         // n
    size_t u_bytes = ((size_t)n * 4 + 511) & ~(size_t)511;
    float*  dis5   = (float*)(ws + 1024 + u_bytes); // 5n

    init_ws<<<1, 64, 0, stream>>>(acc, abl, counts, v);
    pass_a<<<2048, 256, 0, stream>>>(feat, proxy, tgt, dis5, counts, n);
    for (int it = 0; it < 5; ++it) {
        sk_accum<<<1024, 256, 0, stream>>>(dis5, tgt, v, u, acc, n);
        sk_finalize<<<1, 64, 0, stream>>>(acc, v);
    }
    pass_c<<<1024, 256, 0, stream>>>(dis5, tgt, u, v, abl, n);
    finalize<<<1, 256, 0, stream>>>(proxy, abl, counts, (float*)d_out);
}

// Round 2
// 407.056 us; speedup vs baseline: 1.1482x; 1.1482x over previous
//
#include <hip/hip_runtime.h>
#include <math.h>

#define NC 10      // classes
#define NP 5       // proxies per class
#define NCP 50     // NC*NP
#define ND 256     // feature dim
#define FTEMP 0.05f
#define FEPS  0.05f

// ---------------- workspace layout ----------------
// [0, 2400)      double acc[6][50]   sinkhorn col accumulators (slot i = iter i; slot 0 unused)
// [2400, 2640)   double abl[30]      A[10], B[10], L[10]
// [2640, 2680)   int    counts[10]
// [4096, +4n)    float  u[n]
// [align512]     float  dis5[5n]

__device__ inline void lds_fadd(float* p, float v) {
    __hip_atomic_fetch_add(p, v, __ATOMIC_RELAXED, __HIP_MEMORY_SCOPE_WORKGROUP);
}

__global__ __launch_bounds__(512) void init_ws(double* __restrict__ acc,
                                               double* __restrict__ abl,
                                               int* __restrict__ counts) {
    int i = threadIdx.x;
    if (i < 6 * NCP) acc[i] = 0.0;
    if (i < 3 * NC) abl[i] = 0.0;
    if (i < NC) counts[i] = 0;
}

// One wave per row: coalesced float4 row load (prefetched one row ahead),
// dot with the 5 proxies of the row's class (LDS), butterfly-reduce 6 scalars.
// Also folds sinkhorn iteration 1 (v0 = 1): u1 = 1/clip(sum_j d_j),
// acc1[t][j] += d_j * u1  via native f32 LDS atomics -> f64 global atomics.
__global__ __launch_bounds__(512) void pass_a(const float* __restrict__ feat,
                                              const float* __restrict__ proxy,
                                              const int* __restrict__ tgt,
                                              float* __restrict__ dis5,
                                              int* __restrict__ counts,
                                              double* __restrict__ acc1, int n) {
    __shared__ float4 sp[NCP * 64];   // 51200 B: all 50 proxies
    __shared__ float sacc[NCP];
    __shared__ int scnt[NC];
    for (int i = threadIdx.x; i < NCP * 64; i += blockDim.x)
        sp[i] = reinterpret_cast<const float4*>(proxy)[i];
    if (threadIdx.x < NCP) sacc[threadIdx.x] = 0.0f;
    if (threadIdx.x < NC) scnt[threadIdx.x] = 0;
    __syncthreads();

    const int lane = threadIdx.x & 63;
    const int wid  = (blockIdx.x * blockDim.x + threadIdx.x) >> 6;
    const int nw   = (gridDim.x * blockDim.x) >> 6;
    const float4* f4 = reinterpret_cast<const float4*>(feat);

    if (wid < n) {
        int   t = tgt[wid];
        float4 x = f4[(size_t)wid * 64 + lane];
        for (int r = wid; r < n; r += nw) {
            // prefetch next row while we reduce this one
            const int rn = r + nw;
            float4 xn; int tn = 0;
            if (rn < n) { xn = f4[(size_t)rn * 64 + lane]; tn = tgt[rn]; }

            const float4* pp = &sp[t * (NP * 64) + lane];
            float n2 = x.x * x.x + x.y * x.y + x.z * x.z + x.w * x.w;
            float4 p0 = pp[0], p1 = pp[64], p2 = pp[128], p3 = pp[192], p4 = pp[256];
            float d0 = x.x * p0.x + x.y * p0.y + x.z * p0.z + x.w * p0.w;
            float d1 = x.x * p1.x + x.y * p1.y + x.z * p1.z + x.w * p1.w;
            float d2 = x.x * p2.x + x.y * p2.y + x.z * p2.z + x.w * p2.w;
            float d3 = x.x * p3.x + x.y * p3.y + x.z * p3.z + x.w * p3.w;
            float d4 = x.x * p4.x + x.y * p4.y + x.z * p4.z + x.w * p4.w;
#pragma unroll
            for (int off = 32; off >= 1; off >>= 1) {
                n2 += __shfl_xor(n2, off);
                d0 += __shfl_xor(d0, off);
                d1 += __shfl_xor(d1, off);
                d2 += __shfl_xor(d2, off);
                d3 += __shfl_xor(d3, off);
                d4 += __shfl_xor(d4, off);
            }
            const float inv = 1.0f / fmaxf(sqrtf(n2), 1e-12f);
            const float c0 = fminf(fmaxf(d0 * inv, -10.0f), 10.0f);
            const float c1 = fminf(fmaxf(d1 * inv, -10.0f), 10.0f);
            const float c2 = fminf(fmaxf(d2 * inv, -10.0f), 10.0f);
            const float c3 = fminf(fmaxf(d3 * inv, -10.0f), 10.0f);
            const float c4 = fminf(fmaxf(d4 * inv, -10.0f), 10.0f);
            if (lane < NP) {
                float dj = (lane == 0) ? c0 : (lane == 1) ? c1 : (lane == 2) ? c2
                         : (lane == 3) ? c3 : c4;
                dis5[(size_t)r * NP + lane] = dj;
            }
            if (lane == 0) {
                // sinkhorn iter 1: v0 = 1
                const float den = c0 + c1 + c2 + c3 + c4;
                const float uu = 1.0f / fmaxf(den, 1e-10f);
                float* at = &sacc[t * NP];
                lds_fadd(&at[0], c0 * uu);
                lds_fadd(&at[1], c1 * uu);
                lds_fadd(&at[2], c2 * uu);
                lds_fadd(&at[3], c3 * uu);
                lds_fadd(&at[4], c4 * uu);
                atomicAdd(&scnt[t], 1);
            }
            x = xn; t = tn;
        }
    }
    __syncthreads();
    if (threadIdx.x < NCP) unsafeAtomicAdd(&acc1[threadIdx.x], (double)sacc[threadIdx.x]);
    if (threadIdx.x < NC) atomicAdd(&counts[threadIdx.x], scnt[threadIdx.x]);
}

// Sinkhorn iteration i (i>=2): v_{i-1} = 1/clip(acc_{i-1}) computed locally,
// u_i = 1/clip(dis_r . v_{i-1}), acc_i[t][j] += dis_rj * u_i.
__global__ __launch_bounds__(256) void sk_accum(const float* __restrict__ dis5,
                                                const int* __restrict__ tgt,
                                                const double* __restrict__ acc_prev,
                                                double* __restrict__ acc_next,
                                                float* __restrict__ u,
                                                int n, int last) {
    __shared__ float sv[NCP];
    __shared__ float sacc[NCP];
    if (threadIdx.x < NCP) {
        sv[threadIdx.x] = 1.0f / fmaxf((float)acc_prev[threadIdx.x], 1e-10f);
        sacc[threadIdx.x] = 0.0f;
    }
    __syncthreads();
    const int stride = gridDim.x * blockDim.x;
    for (int r = blockIdx.x * blockDim.x + threadIdx.x; r < n; r += stride) {
        const int t = tgt[r];
        const float* dr = &dis5[(size_t)r * NP];
        float d0 = dr[0], d1 = dr[1], d2 = dr[2], d3 = dr[3], d4 = dr[4];
        const float* vt = &sv[t * NP];
        float den = d0 * vt[0] + d1 * vt[1] + d2 * vt[2] + d3 * vt[3] + d4 * vt[4];
        float uu = 1.0f / fmaxf(den, 1e-10f);
        if (last) u[r] = uu;
        float* at = &sacc[t * NP];
        lds_fadd(&at[0], d0 * uu);
        lds_fadd(&at[1], d1 * uu);
        lds_fadd(&at[2], d2 * uu);
        lds_fadd(&at[3], d3 * uu);
        lds_fadd(&at[4], d4 * uu);
    }
    __syncthreads();
    if (threadIdx.x < NCP) unsafeAtomicAdd(&acc_next[threadIdx.x], (double)sacc[threadIdx.x]);
}

// Per-class A = sum Q*logits, B = sum Q, L = sum lse2 (v_5 from acc5).
__global__ __launch_bounds__(256) void pass_c(const float* __restrict__ dis5,
                                              const int* __restrict__ tgt,
                                              const float* __restrict__ u,
                                              const double* __restrict__ acc5,
                                              double* __restrict__ abl, int n) {
    __shared__ float sv[NCP];
    __shared__ float sA[NC], sB[NC], sL[NC];
    if (threadIdx.x < NCP) sv[threadIdx.x] = 1.0f / fmaxf((float)acc5[threadIdx.x], 1e-10f);
    if (threadIdx.x < NC) { sA[threadIdx.x] = 0.0f; sB[threadIdx.x] = 0.0f; sL[threadIdx.x] = 0.0f; }
    __syncthreads();
    const int stride = gridDim.x * blockDim.x;
    for (int r = blockIdx.x * blockDim.x + threadIdx.x; r < n; r += stride) {
        const int t = tgt[r];
        const float* dr = &dis5[(size_t)r * NP];
        float d[NP];
#pragma unroll
        for (int j = 0; j < NP; ++j) d[j] = dr[j];
        float a[NP], mx = -1e30f;
#pragma unroll
        for (int j = 0; j < NP; ++j) { a[j] = d[j] * (1.0f / FTEMP); mx = fmaxf(mx, a[j]); }
        float s = 0.0f;
#pragma unroll
        for (int j = 0; j < NP; ++j) s += expf(a[j] - mx);
        float lse = mx + logf(s);
        float lg[NP];
#pragma unroll
        for (int j = 0; j < NP; ++j) lg[j] = a[j] - lse;
        float mx2 = -1e30f;
#pragma unroll
        for (int j = 0; j < NP; ++j) mx2 = fmaxf(mx2, lg[j]);
        float s2 = 0.0f;
#pragma unroll
        for (int j = 0; j < NP; ++j) s2 += expf(lg[j] - mx2);
        float lse2 = mx2 + logf(s2);

        const float uu = u[r];
        const float* vt = &sv[t * NP];
        float rowA = 0.0f, rowB = 0.0f;
#pragma unroll
        for (int j = 0; j < NP; ++j) {
            float q = uu * expf(d[j] * (1.0f / FEPS)) * vt[j];
            rowB += q;
            rowA += q * lg[j];
        }
        lds_fadd(&sA[t], rowA);
        lds_fadd(&sB[t], rowB);
        lds_fadd(&sL[t], lse2);
    }
    __syncthreads();
    if (threadIdx.x < NC) {
        unsafeAtomicAdd(&abl[threadIdx.x], (double)sA[threadIdx.x]);
        unsafeAtomicAdd(&abl[NC + threadIdx.x], (double)sB[threadIdx.x]);
        unsafeAtomicAdd(&abl[2 * NC + threadIdx.x], (double)sL[threadIdx.x]);
    }
}

// Single block: proxy Gram + pcon + mle -> scalar
__global__ __launch_bounds__(256) void finalize(const float* __restrict__ proxy,
                                                const double* __restrict__ abl,
                                                const int* __restrict__ counts,
                                                float* __restrict__ out) {
    __shared__ float G[NCP][NCP];
    for (int e = threadIdx.x; e < NCP * NCP; e += blockDim.x) {
        int i = e / NCP, j = e % NCP;
        float s = 0.0f;
        for (int k = 0; k < ND; ++k) s += proxy[i * ND + k] * proxy[j * ND + k];
        G[i][j] = s;
    }
    __syncthreads();

    double local = 0.0;
    for (int task = threadIdx.x; task < NC * NC * NP; task += blockDim.x) {
        int r = task % NP;
        int pi = task / NP;
        int co = pi % NC, c = pi / NC;
        float m[NP], mx = -1e30f;
#pragma unroll
        for (int j = 0; j < NP; ++j) {
            float g = G[c * NP + r][co * NP + j] * (1.0f / FTEMP);
            g = fminf(fmaxf(g, -10.0f), 10.0f);
            m[j] = g;
            mx = fmaxf(mx, g);
        }
        float s = 0.0f;
#pragma unroll
        for (int j = 0; j < NP; ++j) s += expf(m[j] - mx);
        float lse = mx + logf(s);
        float mx2 = -1e30f;
#pragma unroll
        for (int j = 0; j < NP; ++j) mx2 = fmaxf(mx2, m[j] - lse);
        float s2 = 0.0f;
#pragma unroll
        for (int j = 0; j < NP; ++j) s2 += expf(m[j] - lse - mx2);
        float lse2 = mx2 + logf(s2);

        if (co == c) {
            float lirr = m[r] - lse;
            local += -(double)(lirr - lse2) * (1.0 / NP);
        } else {
            local += (double)lse2 * (1.0 / NP);
        }
    }
    __shared__ double red[256];
    red[threadIdx.x] = local;
    __syncthreads();
    for (int off = 128; off >= 1; off >>= 1) {
        if (threadIdx.x < off) red[threadIdx.x] += red[threadIdx.x + off];
        __syncthreads();
    }
    if (threadIdx.x == 0) {
        double pcon = red[0];
        double mle = 0.0;
        for (int c = 0; c < NC; ++c) {
            int cnt = counts[c];
            if (cnt > 0) {
                double A = abl[c], B = abl[NC + c], L = abl[2 * NC + c];
                mle += -(A / B - L) / (double)cnt;
            }
        }
        out[0] = (float)((mle + pcon) / NC);
    }
}

extern "C" void kernel_launch(void* const* d_in, const int* in_sizes, int n_in,
                              void* d_out, int out_size, void* d_ws, size_t ws_size,
                              hipStream_t stream) {
    const float* feat  = (const float*)d_in[0];
    const float* proxy = (const float*)d_in[1];
    const int*   tgt   = (const int*)d_in[2];
    const int n = in_sizes[0] / ND;

    char* ws = (char*)d_ws;
    double* acc    = (double*)ws;                 // [6][50]
    double* abl    = (double*)(ws + 2400);        // 30
    int*    counts = (int*)(ws + 2640);           // 10
    float*  u      = (float*)(ws + 4096);         // n
    size_t u_bytes = ((size_t)n * 4 + 511) & ~(size_t)511;
    float*  dis5   = (float*)(ws + 4096 + u_bytes); // 5n

    init_ws<<<1, 512, 0, stream>>>(acc, abl, counts);
    // pass_a folds sinkhorn iter 1 (writes acc slot 1)
    pass_a<<<768, 512, 0, stream>>>(feat, proxy, tgt, dis5, counts, acc + NCP, n);
    for (int it = 2; it <= 5; ++it) {
        sk_accum<<<512, 256, 0, stream>>>(dis5, tgt, acc + NCP * (it - 1),
                                          acc + NCP * it, u, n, it == 5 ? 1 : 0);
    }
    pass_c<<<512, 256, 0, stream>>>(dis5, tgt, u, acc + NCP * 5, abl, n);
    finalize<<<1, 256, 0, stream>>>(proxy, abl, counts, (float*)d_out);
}

// Round 3
// 233.240 us; speedup vs baseline: 2.0039x; 1.7452x over previous
//
#include <hip/hip_runtime.h>
#include <math.h>

#define NC 10      // classes
#define NP 5       // proxies per class
#define NCP 50     // NC*NP
#define ND 256     // feature dim
#define FTEMP 0.05f
#define FEPS  0.05f

// ---------------- workspace layout ----------------
// [0, 2400)      double acc[6][50]   sinkhorn col accumulators (slot i = iter i)
// [2400, 2560)   double abl[20]      A[10], B[10]
// [2560, 2600)   int    counts[10]
// [2624, 12624)  float  G[50*50]     proxy Gram
// [16384, +4n)   float  u[n]
// [align512]     float  dis8[8n]     clipped dots, stride 8 (5 used)

__device__ inline void lds_fadd(float* p, float v) {
    __hip_atomic_fetch_add(p, v, __ATOMIC_RELAXED, __HIP_MEMORY_SCOPE_WORKGROUP);
}

// DPP wave64 sum on the VALU pipe (no LDS). Full sum lands in lane 63.
template <int CTRL>
__device__ inline float dpp_add(float v) {
    int x = __builtin_amdgcn_update_dpp(0, __builtin_bit_cast(int, v),
                                        CTRL, 0xf, 0xf, true);
    return v + __builtin_bit_cast(float, x);
}
__device__ inline float wave_sum63(float v) {
    v = dpp_add<0x111>(v);   // row_shr:1
    v = dpp_add<0x112>(v);   // row_shr:2
    v = dpp_add<0x114>(v);   // row_shr:4
    v = dpp_add<0x118>(v);   // row_shr:8  -> lanes 15/31/47/63 hold row sums
    v = dpp_add<0x142>(v);   // row_bcast:15
    v = dpp_add<0x143>(v);   // row_bcast:31 -> lane 63 holds wave sum
    return v;
}

__global__ __launch_bounds__(512) void init_ws(double* __restrict__ acc,
                                               double* __restrict__ abl,
                                               int* __restrict__ counts) {
    int i = threadIdx.x;
    if (i < 6 * NCP) acc[i] = 0.0;
    if (i < 2 * NC) abl[i] = 0.0;
    if (i < NC) counts[i] = 0;
}

// Wave per row: coalesced float4 row load (one-row prefetch), 5 proxy dots
// (proxies in LDS), 6 DPP reductions (VALU pipe), lane 63 finishes:
// clip, store dis8, fold sinkhorn iter 1 (v0=1) via single-lane LDS atomics.
__global__ __launch_bounds__(512) void pass_a(const float* __restrict__ feat,
                                              const float* __restrict__ proxy,
                                              const int* __restrict__ tgt,
                                              float* __restrict__ dis8,
                                              int* __restrict__ counts,
                                              double* __restrict__ acc1, int n) {
    __shared__ float4 sp[NCP * 64];   // 51200 B
    __shared__ float sacc[NCP];
    __shared__ int scnt[NC];
    for (int i = threadIdx.x; i < NCP * 64; i += blockDim.x)
        sp[i] = reinterpret_cast<const float4*>(proxy)[i];
    if (threadIdx.x < NCP) sacc[threadIdx.x] = 0.0f;
    if (threadIdx.x < NC) scnt[threadIdx.x] = 0;
    __syncthreads();

    const int lane = threadIdx.x & 63;
    const int wid  = (blockIdx.x * blockDim.x + threadIdx.x) >> 6;
    const int nw   = (gridDim.x * blockDim.x) >> 6;
    const float4* f4 = reinterpret_cast<const float4*>(feat);

    if (wid < n) {
        int   t = tgt[wid];
        float4 x = f4[(size_t)wid * 64 + lane];
        for (int r = wid; r < n; r += nw) {
            const int rn = r + nw;
            float4 xn; int tn = 0;
            if (rn < n) { xn = f4[(size_t)rn * 64 + lane]; tn = tgt[rn]; }

            const float4* pp = &sp[t * (NP * 64) + lane];
            float n2 = x.x * x.x + x.y * x.y + x.z * x.z + x.w * x.w;
            float4 p0 = pp[0], p1 = pp[64], p2 = pp[128], p3 = pp[192], p4 = pp[256];
            float d0 = x.x * p0.x + x.y * p0.y + x.z * p0.z + x.w * p0.w;
            float d1 = x.x * p1.x + x.y * p1.y + x.z * p1.z + x.w * p1.w;
            float d2 = x.x * p2.x + x.y * p2.y + x.z * p2.z + x.w * p2.w;
            float d3 = x.x * p3.x + x.y * p3.y + x.z * p3.z + x.w * p3.w;
            float d4 = x.x * p4.x + x.y * p4.y + x.z * p4.z + x.w * p4.w;

            n2 = wave_sum63(n2);
            d0 = wave_sum63(d0);
            d1 = wave_sum63(d1);
            d2 = wave_sum63(d2);
            d3 = wave_sum63(d3);
            d4 = wave_sum63(d4);

            if (lane == 63) {
                const float inv = 1.0f / fmaxf(sqrtf(n2), 1e-12f);
                const float c0 = fminf(fmaxf(d0 * inv, -10.0f), 10.0f);
                const float c1 = fminf(fmaxf(d1 * inv, -10.0f), 10.0f);
                const float c2 = fminf(fmaxf(d2 * inv, -10.0f), 10.0f);
                const float c3 = fminf(fmaxf(d3 * inv, -10.0f), 10.0f);
                const float c4 = fminf(fmaxf(d4 * inv, -10.0f), 10.0f);
                float4* o = reinterpret_cast<float4*>(&dis8[(size_t)r * 8]);
                o[0] = make_float4(c0, c1, c2, c3);
                o[1] = make_float4(c4, 0.0f, 0.0f, 0.0f);
                // sinkhorn iter 1 (v0 = 1)
                const float den = c0 + c1 + c2 + c3 + c4;
                const float uu = 1.0f / fmaxf(den, 1e-10f);
                float* at = &sacc[t * NP];
                lds_fadd(&at[0], c0 * uu);
                lds_fadd(&at[1], c1 * uu);
                lds_fadd(&at[2], c2 * uu);
                lds_fadd(&at[3], c3 * uu);
                lds_fadd(&at[4], c4 * uu);
                atomicAdd(&scnt[t], 1);
            }
            x = xn; t = tn;
        }
    }
    __syncthreads();
    if (threadIdx.x < NCP) unsafeAtomicAdd(&acc1[threadIdx.x], (double)sacc[threadIdx.x]);
    if (threadIdx.x < NC) atomicAdd(&counts[threadIdx.x], scnt[threadIdx.x]);
}

// Sinkhorn iteration i (i>=2): v_{i-1} = 1/clip(acc_{i-1}) locally,
// u_i = 1/clip(dis_r . v_{i-1}), acc_i[t][j] += dis_rj * u_i.
__global__ __launch_bounds__(256) void sk_accum(const float* __restrict__ dis8,
                                                const int* __restrict__ tgt,
                                                const double* __restrict__ acc_prev,
                                                double* __restrict__ acc_next,
                                                float* __restrict__ u,
                                                int n, int last) {
    __shared__ float sv[NCP];
    __shared__ float sacc[NCP];
    if (threadIdx.x < NCP) {
        sv[threadIdx.x] = 1.0f / fmaxf((float)acc_prev[threadIdx.x], 1e-10f);
        sacc[threadIdx.x] = 0.0f;
    }
    __syncthreads();
    const int stride = gridDim.x * blockDim.x;
    const float4* d4p = reinterpret_cast<const float4*>(dis8);
    for (int r = blockIdx.x * blockDim.x + threadIdx.x; r < n; r += stride) {
        const int t = tgt[r];
        float4 lo = d4p[(size_t)r * 2];
        float4 hi = d4p[(size_t)r * 2 + 1];
        const float* vt = &sv[t * NP];
        float den = lo.x * vt[0] + lo.y * vt[1] + lo.z * vt[2] + lo.w * vt[3] + hi.x * vt[4];
        float uu = 1.0f / fmaxf(den, 1e-10f);
        if (last) u[r] = uu;
        float* at = &sacc[t * NP];
        lds_fadd(&at[0], lo.x * uu);
        lds_fadd(&at[1], lo.y * uu);
        lds_fadd(&at[2], lo.z * uu);
        lds_fadd(&at[3], lo.w * uu);
        lds_fadd(&at[4], hi.x * uu);
    }
    __syncthreads();
    if (threadIdx.x < NCP) unsafeAtomicAdd(&acc_next[threadIdx.x], (double)sacc[threadIdx.x]);
}

// Per-class A = sum Q*logits, B = sum Q.  (L = logsumexp(log_softmax) == 0
// to ~1e-7, dropped.)  exp(d/EPS) = exp(a-mx)*exp(mx) reuses softmax exps.
__global__ __launch_bounds__(256) void pass_c(const float* __restrict__ dis8,
                                              const int* __restrict__ tgt,
                                              const float* __restrict__ u,
                                              const double* __restrict__ acc5,
                                              double* __restrict__ abl, int n) {
    __shared__ float sv[NCP];
    __shared__ float sA[NC], sB[NC];
    if (threadIdx.x < NCP) sv[threadIdx.x] = 1.0f / fmaxf((float)acc5[threadIdx.x], 1e-10f);
    if (threadIdx.x < NC) { sA[threadIdx.x] = 0.0f; sB[threadIdx.x] = 0.0f; }
    __syncthreads();
    const int stride = gridDim.x * blockDim.x;
    const float4* d4p = reinterpret_cast<const float4*>(dis8);
    for (int r = blockIdx.x * blockDim.x + threadIdx.x; r < n; r += stride) {
        const int t = tgt[r];
        float4 lo = d4p[(size_t)r * 2];
        float4 hi = d4p[(size_t)r * 2 + 1];
        float d[NP] = {lo.x, lo.y, lo.z, lo.w, hi.x};
        float a[NP], mx = -1e30f;
#pragma unroll
        for (int j = 0; j < NP; ++j) { a[j] = d[j] * (1.0f / FTEMP); mx = fmaxf(mx, a[j]); }
        float e[NP], s = 0.0f;
#pragma unroll
        for (int j = 0; j < NP; ++j) { e[j] = expf(a[j] - mx); s += e[j]; }
        float lse = mx + logf(s);
        const float es = expf(mx);           // exp(d/EPS) = e[j]*es
        const float uu = u[r];
        const float* vt = &sv[t * NP];
        float rowA = 0.0f, rowB = 0.0f;
#pragma unroll
        for (int j = 0; j < NP; ++j) {
            float q = uu * vt[j] * e[j] * es;
            rowB += q;
            rowA += q * (a[j] - lse);
        }
        lds_fadd(&sA[t], rowA);
        lds_fadd(&sB[t], rowB);
    }
    __syncthreads();
    if (threadIdx.x < NC) {
        unsafeAtomicAdd(&abl[threadIdx.x], (double)sA[threadIdx.x]);
        unsafeAtomicAdd(&abl[NC + threadIdx.x], (double)sB[threadIdx.x]);
    }
}

// Proxy Gram: block b = (c,co) pair, 25 dots, 2 lanes per dot.
__global__ __launch_bounds__(64) void gram(const float* __restrict__ proxy,
                                           float* __restrict__ G) {
    const int c = blockIdx.x / NC, co = blockIdx.x % NC;
    const int lane = threadIdx.x;
    const int p = lane >> 1, h = lane & 1;
    float s = 0.0f;
    int i = 0, j = 0;
    if (p < 25) {
        i = c * NP + p / 5;
        j = co * NP + p % 5;
        const float4* pi = reinterpret_cast<const float4*>(&proxy[i * ND]);
        const float4* pj = reinterpret_cast<const float4*>(&proxy[j * ND]);
#pragma unroll 8
        for (int k = h * 32; k < h * 32 + 32; ++k) {
            float4 aa = pi[k], bb = pj[k];
            s += aa.x * bb.x + aa.y * bb.y + aa.z * bb.z + aa.w * bb.w;
        }
    }
    s += __shfl_xor(s, 1);
    if (p < 25 && h == 0) G[i * NCP + j] = s;
}

// pcon (500 tiny lse tasks over G) + mle from abl/counts -> scalar out.
__global__ __launch_bounds__(512) void pcon_mle(const float* __restrict__ G,
                                                const double* __restrict__ abl,
                                                const int* __restrict__ counts,
                                                float* __restrict__ out) {
    const int tid = threadIdx.x;
    double local = 0.0;
    if (tid < NC * NC * NP) {
        int r = tid % NP;
        int pi = tid / NP;
        int co = pi % NC, c = pi / NC;
        float m[NP], mx = -1e30f;
#pragma unroll
        for (int j = 0; j < NP; ++j) {
            float g = G[(c * NP + r) * NCP + co * NP + j] * (1.0f / FTEMP);
            g = fminf(fmaxf(g, -10.0f), 10.0f);
            m[j] = g;
            mx = fmaxf(mx, g);
        }
        float s = 0.0f;
#pragma unroll
        for (int j = 0; j < NP; ++j) s += expf(m[j] - mx);
        float lse = mx + logf(s);
        float mx2 = -1e30f;
#pragma unroll
        for (int j = 0; j < NP; ++j) mx2 = fmaxf(mx2, m[j] - lse);
        float s2 = 0.0f;
#pragma unroll
        for (int j = 0; j < NP; ++j) s2 += expf(m[j] - lse - mx2);
        float lse2 = mx2 + logf(s2);
        if (co == c) local = -(double)((m[r] - lse) - lse2) * (1.0 / NP);
        else         local = (double)lse2 * (1.0 / NP);
    }
    __shared__ double red[512];
    red[tid] = local;
    __syncthreads();
    for (int off = 256; off >= 1; off >>= 1) {
        if (tid < off) red[tid] += red[tid + off];
        __syncthreads();
    }
    if (tid == 0) {
        double pcon = red[0];
        double mle = 0.0;
        for (int c = 0; c < NC; ++c) {
            int cnt = counts[c];
            if (cnt > 0) {
                double A = abl[c], B = abl[NC + c];
                mle += -(A / B) / (double)cnt;
            }
        }
        out[0] = (float)((mle + pcon) / NC);
    }
}

extern "C" void kernel_launch(void* const* d_in, const int* in_sizes, int n_in,
                              void* d_out, int out_size, void* d_ws, size_t ws_size,
                              hipStream_t stream) {
    const float* feat  = (const float*)d_in[0];
    const float* proxy = (const float*)d_in[1];
    const int*   tgt   = (const int*)d_in[2];
    const int n = in_sizes[0] / ND;

    char* ws = (char*)d_ws;
    double* acc    = (double*)ws;                  // [6][50]
    double* abl    = (double*)(ws + 2400);         // 20
    int*    counts = (int*)(ws + 2560);            // 10
    float*  G      = (float*)(ws + 2624);          // 2500
    float*  u      = (float*)(ws + 16384);         // n
    size_t u_bytes = ((size_t)n * 4 + 511) & ~(size_t)511;
    float*  dis8   = (float*)(ws + 16384 + u_bytes); // 8n

    init_ws<<<1, 512, 0, stream>>>(acc, abl, counts);
    pass_a<<<768, 512, 0, stream>>>(feat, proxy, tgt, dis8, counts, acc + NCP, n);
    for (int it = 2; it <= 5; ++it) {
        sk_accum<<<512, 256, 0, stream>>>(dis8, tgt, acc + NCP * (it - 1),
                                          acc + NCP * it, u, n, it == 5 ? 1 : 0);
    }
    pass_c<<<512, 256, 0, stream>>>(dis8, tgt, u, acc + NCP * 5, abl, n);
    gram<<<NC * NC, 64, 0, stream>>>(proxy, G);
    pcon_mle<<<1, 512, 0, stream>>>(G, abl, counts, (float*)d_out);
}